// Round 1
// baseline (170.748 us; speedup 1.0000x reference)
//
#include <hip/hip_runtime.h>
#include <hip/hip_bf16.h>

typedef __attribute__((ext_vector_type(8))) short short8;
typedef __attribute__((ext_vector_type(4))) float float4v;

#define DEV __device__ __forceinline__

constexpr int SEQ = 1024;
constexpr int DM  = 1024;    // d_model
constexpr int KVD = 256;     // kv dim
constexpr int MTOK = 4096;   // batch*seq

// ---- helpers ----------------------------------------------------------------

DEV void load_lds16(const void* g, void* l) {
  __builtin_amdgcn_global_load_lds(
      (const __attribute__((address_space(1))) unsigned int*)g,
      (__attribute__((address_space(3))) unsigned int*)l, 16, 0, 0);
}

DEV unsigned short f2bf(float f) {   // fp32 -> bf16 RNE
  unsigned int u = __float_as_uint(f);
  u += 0x7fffu + ((u >> 16) & 1u);
  return (unsigned short)(u >> 16);
}

// ---- prep: fp32->bf16 conversions + rope table ------------------------------
// conv units are float4-sized. layout of Wqkvb: rows [0,1024)=Wq, [1024,1280)=Wk,
// [1280,1536)=Wv, all [*][1024] row-major (NT GEMM B operand).

__global__ __launch_bounds__(256)
void prep_kernel(const float* __restrict__ x,  const float* __restrict__ Wq,
                 const float* __restrict__ Wk, const float* __restrict__ Wv,
                 const float* __restrict__ Wo,
                 unsigned short* __restrict__ xb, unsigned short* __restrict__ Wqkvb,
                 unsigned short* __restrict__ Wob,
                 float* __restrict__ rc, float* __restrict__ rs)
{
  const int NX  = (MTOK*DM)/4;          // 1048576
  const int NWQ = (DM*DM)/4;            // 262144
  const int NWK = (KVD*DM)/4;           // 65536
  const int NCONV = NX + NWQ + 2*NWK + NWQ; // 1703936
  int id = blockIdx.x*256 + threadIdx.x;
  if (id < NCONV) {
    const float* src; unsigned short* dst; int u;
    if      (id < NX)            { src = x;  dst = xb;                     u = id; }
    else if (id < NX+NWQ)        { src = Wq; dst = Wqkvb;                  u = id-NX; }
    else if (id < NX+NWQ+NWK)    { src = Wk; dst = Wqkvb + DM*DM;          u = id-(NX+NWQ); }
    else if (id < NX+NWQ+2*NWK)  { src = Wv; dst = Wqkvb + DM*DM+KVD*DM;   u = id-(NX+NWQ+NWK); }
    else                         { src = Wo; dst = Wob;                    u = id-(NX+NWQ+2*NWK); }
    float4 v = ((const float4*)src)[u];
    ushort4 o;
    o.x = f2bf(v.x); o.y = f2bf(v.y); o.z = f2bf(v.z); o.w = f2bf(v.w);
    ((ushort4*)dst)[u] = o;
  } else {
    int id2 = id - NCONV;                 // [0, 1024*512)
    if (id2 < SEQ*512) {
      int pos = id2 >> 9, i = id2 & 511;
      // theta = 10000^(-i/512) = exp2(-i * log2(10000)/512)
      float theta = exp2f((float)i * (-13.287712379549449f/512.0f));
      float ang = (float)pos * theta;
      float sv, cv; sincosf(ang, &sv, &cv);
      rc[id2] = cv; rs[id2] = sv;
    }
  }
}

// ---- NT bf16 MFMA GEMM: C[m][n] = sum_k A[m][k]*B[n][k] ---------------------
// 128x128 tile, BK=32, 256 threads = 4 waves (2x2), each wave 64x64 = 4x4 frags.
// MODE 0: fused QKV epilogue (rope Q -> Qb, rope K -> Kb, V -> Vt transposed)
// MODE 2: out-projection epilogue (fp32 + bias -> outF)

template<int MODE>
__global__ __launch_bounds__(256)
void gemm_nt(const unsigned short* __restrict__ A, const unsigned short* __restrict__ Bw,
             unsigned short* __restrict__ outQ, unsigned short* __restrict__ outK,
             unsigned short* __restrict__ outVt, float* __restrict__ outF,
             const float* __restrict__ bias,
             const float* __restrict__ rc, const float* __restrict__ rs)
{
  __shared__ __align__(16) unsigned short As[128*32];
  __shared__ __align__(16) unsigned short Bs[128*32];
  const int tid = threadIdx.x;
  const int w  = tid >> 6, l = tid & 63;
  const int lg = l >> 4, ll = l & 15;
  const int wr = w >> 1, wc = w & 1;
  const int brow = blockIdx.x * 128, bcol = blockIdx.y * 128;

  float4v acc[4][4];
#pragma unroll
  for (int i = 0; i < 4; ++i)
#pragma unroll
    for (int j = 0; j < 4; ++j) acc[i][j] = (float4v){0.f,0.f,0.f,0.f};

  auto stage = [&](int kt) {
#pragma unroll
    for (int c = 0; c < 2; ++c) {
      int t = c*256 + w*64 + l;            // chunk id 0..511 (16B chunks)
      int row = t >> 2, ch = t & 3;
      int cl = ch ^ (row & 3);             // read-side XOR swizzle, pre-applied to source
      load_lds16(A  + (size_t)(brow+row)*DM + kt + cl*8, &As[(c*256 + w*64)*8]);
      load_lds16(Bw + (size_t)(bcol+row)*DM + kt + cl*8, &Bs[(c*256 + w*64)*8]);
    }
  };

  stage(0);
  for (int kt = 0; kt < DM/32; ++kt) {
    __syncthreads();
    short8 af[4], bf[4];
#pragma unroll
    for (int mi = 0; mi < 4; ++mi) {
      int row = wr*64 + mi*16 + ll;
      af[mi] = *(const short8*)&As[row*32 + ((lg ^ (row&3)) << 3)];
    }
#pragma unroll
    for (int ni = 0; ni < 4; ++ni) {
      int col = wc*64 + ni*16 + ll;
      bf[ni] = *(const short8*)&Bs[col*32 + ((lg ^ (col&3)) << 3)];
    }
#pragma unroll
    for (int mi = 0; mi < 4; ++mi)
#pragma unroll
      for (int ni = 0; ni < 4; ++ni)
        acc[mi][ni] = __builtin_amdgcn_mfma_f32_16x16x32_bf16(af[mi], bf[ni], acc[mi][ni], 0,0,0);
    __syncthreads();
    if (kt + 1 < DM/32) stage((kt+1)*32);
  }

  // epilogue: C/D layout col=lane&15, row=(lane>>4)*4+r   [measured m89/m91]
#pragma unroll
  for (int mi = 0; mi < 4; ++mi)
#pragma unroll
    for (int ni = 0; ni < 4; ++ni)
#pragma unroll
      for (int r = 0; r < 4; ++r) {
        int m = brow + wr*64 + mi*16 + lg*4 + r;
        int n = bcol + wc*64 + ni*16 + ll;
        float v = acc[mi][ni][r];
        if constexpr (MODE == 0) {
          // rope partner: col n^1 lives in lane l^1 (same frag/reg)
          float p = __shfl_xor(v, 1);
          if (n < DM) {                       // Q (always true branch-uniform per block)
            int pos = m & (SEQ-1);
            int i = n >> 1;
            float ct = rc[pos*512 + i], st = rs[pos*512 + i];
            v = (n & 1) ? (v*ct + p*st) : (v*ct - p*st);
            outQ[(size_t)m*DM + n] = f2bf(v);
          } else if (n < DM + KVD) {          // K
            int nk = n - DM;
            int pos = m & (SEQ-1);
            int i = nk >> 1;
            float ct = rc[pos*512 + i], st = rs[pos*512 + i];
            v = (nk & 1) ? (v*ct + p*st) : (v*ct - p*st);
            outK[(size_t)m*KVD + nk] = f2bf(v);
          } else {                            // V -> transposed store Vt[b][nv][s]
            int nv = n - DM - KVD;
            outVt[((size_t)(m >> 10)*KVD + nv)*SEQ + (m & (SEQ-1))] = f2bf(v);
          }
        } else {
          outF[(size_t)m*DM + n] = v + bias[n];
        }
      }
}

// ---- causal GQA flash attention --------------------------------------------
// grid (16 qtiles, 32 q-heads, 4 batch); 256 thr = 4 waves x 16 q-rows; KVBLK=64.
// Q frag in regs; K_lds[64][32], V_lds[32][64] staged via global_load_lds with
// XOR swizzle; P relayout via per-wave swizzled LDS.

__global__ __launch_bounds__(256)
void attn_kernel(const unsigned short* __restrict__ Qb, const unsigned short* __restrict__ Kb,
                 const unsigned short* __restrict__ Vtb, unsigned short* __restrict__ Ob)
{
  __shared__ __align__(16) unsigned short Kl[64*32];
  __shared__ __align__(16) unsigned short Vl[32*64];
  __shared__ __align__(16) unsigned short Pl[4][16*64];
  const int tid = threadIdx.x;
  const int w  = tid >> 6, l = tid & 63;
  const int lg = l >> 4, ll = l & 15;
  const int qt = (int)(gridDim.x - 1 - blockIdx.x);   // descending: heavy blocks first
  const int h  = blockIdx.y;
  const int b  = blockIdx.z;
  const int hk = h >> 2;

  // A-operand Q fragment: row = lane%16 -> q row w*16+ll ; k = d = (lane/16)*8+j
  const size_t qtok = (size_t)b*SEQ + qt*64 + w*16 + ll;
  short8 qf = *(const short8*)&Qb[qtok*DM + h*32 + (lg << 3)];

  float4v o0 = (float4v){0,0,0,0}, o1 = (float4v){0,0,0,0};
  float mrow[4] = {-1e30f,-1e30f,-1e30f,-1e30f};
  float lrow[4] = {0.f,0.f,0.f,0.f};
  const float scale = 0.17677669529663687f;   // 1/sqrt(32)

  for (int kvt = 0; kvt <= qt; ++kvt) {
    const int kv0 = kvt*64;
    {
      int t = w*64 + l;                       // 256 chunks each for K and V tiles
      int kv = t >> 2, c = t & 3, cl = c ^ (kv & 3);
      load_lds16(&Kb[((size_t)b*SEQ + kv0 + kv)*KVD + hk*32 + cl*8], &Kl[(w*64)*8]);
      int d = t >> 3, c8 = t & 7, cl8 = c8 ^ (d & 7);
      load_lds16(&Vtb[((size_t)b*KVD + hk*32 + d)*SEQ + kv0 + cl8*8], &Vl[(w*64)*8]);
    }
    __syncthreads();

    // S = Q K^T (rows q = lg*4+r, cols kv = ni*16+ll)
    float sc[4][4];
#pragma unroll
    for (int ni = 0; ni < 4; ++ni) {
      int kv = ni*16 + ll;
      short8 kf = *(const short8*)&Kl[kv*32 + ((lg ^ (kv&3)) << 3)];
      float4v s = __builtin_amdgcn_mfma_f32_16x16x32_bf16(qf, kf, (float4v){0,0,0,0}, 0,0,0);
#pragma unroll
      for (int r = 0; r < 4; ++r) {
        float v = s[r] * scale;
        if (kvt == qt) {
          int qq = w*16 + lg*4 + r;
          if (kv > qq) v = -1e30f;            // causal mask (within diagonal tile)
        }
        sc[ni][r] = v;
      }
    }

    // online softmax, per q-row (r); row spans 16 lanes (bits 0..3) x 4 ni regs
    float mt[4], corr[4], ts[4];
#pragma unroll
    for (int r = 0; r < 4; ++r)
      mt[r] = fmaxf(fmaxf(sc[0][r], sc[1][r]), fmaxf(sc[2][r], sc[3][r]));
#pragma unroll
    for (int off = 1; off <= 8; off <<= 1)
#pragma unroll
      for (int r = 0; r < 4; ++r) mt[r] = fmaxf(mt[r], __shfl_xor(mt[r], off));

    float pr[4][4];
#pragma unroll
    for (int r = 0; r < 4; ++r) {
      float mn = fmaxf(mrow[r], mt[r]);
      corr[r] = __expf(mrow[r] - mn);
      mrow[r] = mn;
      float s0 = 0.f;
#pragma unroll
      for (int ni = 0; ni < 4; ++ni) { float p = __expf(sc[ni][r] - mn); pr[ni][r] = p; s0 += p; }
      ts[r] = s0;
    }
#pragma unroll
    for (int off = 1; off <= 8; off <<= 1)
#pragma unroll
      for (int r = 0; r < 4; ++r) ts[r] += __shfl_xor(ts[r], off);
#pragma unroll
    for (int r = 0; r < 4; ++r) {
      lrow[r] = lrow[r]*corr[r] + ts[r];
      o0[r] *= corr[r]; o1[r] *= corr[r];
    }

    // P -> per-wave LDS (bf16, XOR-swizzled rows) for A-operand relayout
    unsigned short* Pw = &Pl[w][0];
#pragma unroll
    for (int ni = 0; ni < 4; ++ni)
#pragma unroll
      for (int r = 0; r < 4; ++r) {
        int row = lg*4 + r;
        int col = ni*16 + ll;
        Pw[row*64 + (col ^ ((row & 7) << 3))] = f2bf(pr[ni][r]);
      }

    // O += P V   (K-dim = kv, 2 steps of 32)
#pragma unroll
    for (int kk = 0; kk < 2; ++kk) {
      int kvb = kk*32 + (lg << 3);
      short8 pf = *(const short8*)&Pw[ll*64 + (kvb ^ ((ll & 7) << 3))];
      int d0 = ll;
      short8 vf0 = *(const short8*)&Vl[d0*64 + (kvb ^ ((d0 & 7) << 3))];
      o0 = __builtin_amdgcn_mfma_f32_16x16x32_bf16(pf, vf0, o0, 0,0,0);
      int d1 = 16 + ll;
      short8 vf1 = *(const short8*)&Vl[d1*64 + (kvb ^ ((d1 & 7) << 3))];
      o1 = __builtin_amdgcn_mfma_f32_16x16x32_bf16(pf, vf1, o1, 0,0,0);
    }
    __syncthreads();   // all waves done with Kl/Vl before next stage
  }

#pragma unroll
  for (int r = 0; r < 4; ++r) {
    float inv = 1.f / lrow[r];
    size_t tok = (size_t)b*SEQ + qt*64 + w*16 + lg*4 + r;
    Ob[tok*DM + h*32 + ll]      = f2bf(o0[r] * inv);
    Ob[tok*DM + h*32 + 16 + ll] = f2bf(o1[r] * inv);
  }
}

// ---- launch -----------------------------------------------------------------

extern "C" void kernel_launch(void* const* d_in, const int* in_sizes, int n_in,
                              void* d_out, int out_size, void* d_ws, size_t ws_size,
                              hipStream_t stream)
{
  const float* x  = (const float*)d_in[0];
  const float* Wq = (const float*)d_in[1];
  const float* Wk = (const float*)d_in[2];
  const float* Wv = (const float*)d_in[3];
  const float* Wo = (const float*)d_in[4];
  const float* bo = (const float*)d_in[5];
  float* out = (float*)d_out;

  char* ws = (char*)d_ws;
  const size_t MB = 1u << 20;
  unsigned short* xb    = (unsigned short*)(ws + 0*MB);   // 8 MB
  unsigned short* Wqkvb = (unsigned short*)(ws + 8*MB);   // 3 MB [1536][1024]
  unsigned short* Wob   = (unsigned short*)(ws + 11*MB);  // 2 MB
  float*          rc    = (float*)(ws + 13*MB);           // 2 MB [1024][512]
  float*          rs    = (float*)(ws + 15*MB);           // 2 MB
  unsigned short* Qb    = (unsigned short*)(ws + 17*MB);  // 8 MB [4096][1024]
  unsigned short* Kb    = (unsigned short*)(ws + 25*MB);  // 2 MB [4096][256]
  unsigned short* Vt    = (unsigned short*)(ws + 27*MB);  // 2 MB [4][256][1024]
  unsigned short* Ob    = (unsigned short*)(ws + 29*MB);  // 8 MB [4096][1024]
  if (ws_size < 37*MB) return;   // insufficient scratch; bail (will fail validation loudly)

  {
    const int total = 1703936 + SEQ*512;   // conv units + rope units
    const int blocks = (total + 255) / 256;
    prep_kernel<<<blocks, 256, 0, stream>>>(x, Wq, Wk, Wv, Wo, xb, Wqkvb, Wob, rc, rs);
  }
  // fused QKV projection: N = 1536 (Q 1024 | K 256 | V 256)
  gemm_nt<0><<<dim3(32, 12), 256, 0, stream>>>(xb, Wqkvb, Qb, Kb, Vt, nullptr, nullptr, rc, rs);
  attn_kernel<<<dim3(16, 32, 4), 256, 0, stream>>>(Qb, Kb, Vt, Ob);
  // out projection + bias
  gemm_nt<2><<<dim3(32, 8), 256, 0, stream>>>(Ob, Wob, nullptr, nullptr, nullptr, out, bo, rc, rs);
}

// Round 2
// 148.435 us; speedup vs baseline: 1.1503x; 1.1503x over previous
//
#include <hip/hip_runtime.h>
#include <hip/hip_bf16.h>

typedef __attribute__((ext_vector_type(8))) short short8;
typedef __attribute__((ext_vector_type(4))) float float4v;

#define DEV __device__ __forceinline__

constexpr int SEQ = 1024;
constexpr int DM  = 1024;    // d_model
constexpr int KVD = 256;     // kv dim
constexpr int MTOK = 4096;   // batch*seq

// 1/sqrt(32) * log2(e) — folded into Q so softmax uses raw v_exp_f32 (2^x)
constexpr float QSCALE = 0.25503487660444f;

// ---- helpers ----------------------------------------------------------------

DEV void load_lds16(const void* g, void* l) {
  __builtin_amdgcn_global_load_lds(
      (const __attribute__((address_space(1))) unsigned int*)g,
      (__attribute__((address_space(3))) unsigned int*)l, 16, 0, 0);
}

DEV unsigned short f2bf(float f) {   // fp32 -> bf16 RNE
  unsigned int u = __float_as_uint(f);
  u += 0x7fffu + ((u >> 16) & 1u);
  return (unsigned short)(u >> 16);
}

DEV float fexp2(float x) {           // raw 2^x (no libm fixups)
  float y;
  asm("v_exp_f32 %0, %1" : "=v"(y) : "v"(x));
  return y;
}

// ---- prep: fp32->bf16 conversions + rope table ------------------------------

__global__ __launch_bounds__(256)
void prep_kernel(const float* __restrict__ x,  const float* __restrict__ Wq,
                 const float* __restrict__ Wk, const float* __restrict__ Wv,
                 const float* __restrict__ Wo,
                 unsigned short* __restrict__ xb, unsigned short* __restrict__ Wqkvb,
                 unsigned short* __restrict__ Wob,
                 float* __restrict__ rc, float* __restrict__ rs)
{
  const int NX  = (MTOK*DM)/4;          // 1048576
  const int NWQ = (DM*DM)/4;            // 262144
  const int NWK = (KVD*DM)/4;           // 65536
  const int NCONV = NX + NWQ + 2*NWK + NWQ; // 1703936
  int id = blockIdx.x*256 + threadIdx.x;
  if (id < NCONV) {
    const float* src; unsigned short* dst; int u;
    if      (id < NX)            { src = x;  dst = xb;                     u = id; }
    else if (id < NX+NWQ)        { src = Wq; dst = Wqkvb;                  u = id-NX; }
    else if (id < NX+NWQ+NWK)    { src = Wk; dst = Wqkvb + DM*DM;          u = id-(NX+NWQ); }
    else if (id < NX+NWQ+2*NWK)  { src = Wv; dst = Wqkvb + DM*DM+KVD*DM;   u = id-(NX+NWQ+NWK); }
    else                         { src = Wo; dst = Wob;                    u = id-(NX+NWQ+2*NWK); }
    float4 v = ((const float4*)src)[u];
    ushort4 o;
    o.x = f2bf(v.x); o.y = f2bf(v.y); o.z = f2bf(v.z); o.w = f2bf(v.w);
    ((ushort4*)dst)[u] = o;
  } else {
    int id2 = id - NCONV;                 // [0, 1024*512)
    if (id2 < SEQ*512) {
      int pos = id2 >> 9, i = id2 & 511;
      float theta = exp2f((float)i * (-13.287712379549449f/512.0f));
      float ang = (float)pos * theta;
      float sv, cv; sincosf(ang, &sv, &cv);
      rc[id2] = cv; rs[id2] = sv;
    }
  }
}

// ---- NT bf16 MFMA GEMM: C[m][n] = sum_k A[m][k]*B[n][k] ---------------------
// MODE 0: fused QKV epilogue (rope+prescale Q -> Qb, rope K -> Kb, V -> Vt)
// MODE 2: out-projection epilogue (fp32 + bias -> outF)

template<int MODE>
__global__ __launch_bounds__(256)
void gemm_nt(const unsigned short* __restrict__ A, const unsigned short* __restrict__ Bw,
             unsigned short* __restrict__ outQ, unsigned short* __restrict__ outK,
             unsigned short* __restrict__ outVt, float* __restrict__ outF,
             const float* __restrict__ bias,
             const float* __restrict__ rc, const float* __restrict__ rs)
{
  __shared__ __align__(16) unsigned short As[128*32];
  __shared__ __align__(16) unsigned short Bs[128*32];
  const int tid = threadIdx.x;
  const int w  = tid >> 6, l = tid & 63;
  const int lg = l >> 4, ll = l & 15;
  const int wr = w >> 1, wc = w & 1;
  const int brow = blockIdx.x * 128, bcol = blockIdx.y * 128;

  float4v acc[4][4];
#pragma unroll
  for (int i = 0; i < 4; ++i)
#pragma unroll
    for (int j = 0; j < 4; ++j) acc[i][j] = (float4v){0.f,0.f,0.f,0.f};

  auto stage = [&](int kt) {
#pragma unroll
    for (int c = 0; c < 2; ++c) {
      int t = c*256 + w*64 + l;            // chunk id 0..511 (16B chunks)
      int row = t >> 2, ch = t & 3;
      int cl = ch ^ (row & 3);             // read-side XOR swizzle pre-applied to src
      load_lds16(A  + (size_t)(brow+row)*DM + kt + cl*8, &As[(c*256 + w*64)*8]);
      load_lds16(Bw + (size_t)(bcol+row)*DM + kt + cl*8, &Bs[(c*256 + w*64)*8]);
    }
  };

  stage(0);
  for (int kt = 0; kt < DM/32; ++kt) {
    __syncthreads();
    short8 af[4], bf[4];
#pragma unroll
    for (int mi = 0; mi < 4; ++mi) {
      int row = wr*64 + mi*16 + ll;
      af[mi] = *(const short8*)&As[row*32 + ((lg ^ (row&3)) << 3)];
    }
#pragma unroll
    for (int ni = 0; ni < 4; ++ni) {
      int col = wc*64 + ni*16 + ll;
      bf[ni] = *(const short8*)&Bs[col*32 + ((lg ^ (col&3)) << 3)];
    }
#pragma unroll
    for (int mi = 0; mi < 4; ++mi)
#pragma unroll
      for (int ni = 0; ni < 4; ++ni)
        acc[mi][ni] = __builtin_amdgcn_mfma_f32_16x16x32_bf16(af[mi], bf[ni], acc[mi][ni], 0,0,0);
    __syncthreads();
    if (kt + 1 < DM/32) stage((kt+1)*32);
  }

  // epilogue: C/D layout col=lane&15, row=(lane>>4)*4+r
#pragma unroll
  for (int mi = 0; mi < 4; ++mi)
#pragma unroll
    for (int ni = 0; ni < 4; ++ni)
#pragma unroll
      for (int r = 0; r < 4; ++r) {
        int m = brow + wr*64 + mi*16 + lg*4 + r;
        int n = bcol + wc*64 + ni*16 + ll;
        float v = acc[mi][ni][r];
        if constexpr (MODE == 0) {
          float p = __shfl_xor(v, 1);      // rope partner col n^1 = lane l^1
          if (n < DM) {                    // Q
            int pos = m & (SEQ-1);
            int i = n >> 1;
            float ct = rc[pos*512 + i], st = rs[pos*512 + i];
            v = (n & 1) ? (v*ct + p*st) : (v*ct - p*st);
            outQ[(size_t)m*DM + n] = f2bf(v * QSCALE);
          } else if (n < DM + KVD) {       // K
            int nk = n - DM;
            int pos = m & (SEQ-1);
            int i = nk >> 1;
            float ct = rc[pos*512 + i], st = rs[pos*512 + i];
            v = (nk & 1) ? (v*ct + p*st) : (v*ct - p*st);
            outK[(size_t)m*KVD + nk] = f2bf(v);
          } else {                         // V -> transposed Vt[b][nv][s]
            int nv = n - DM - KVD;
            outVt[((size_t)(m >> 10)*KVD + nv)*SEQ + (m & (SEQ-1))] = f2bf(v);
          }
        } else {
          outF[(size_t)m*DM + n] = v + bias[n];
        }
      }
}

// ---- causal GQA flash attention (v2: KV-group sharing + dbuf) ---------------
// grid (16 qtiles, 8 kv-heads, 4 batch); 512 thr = 8 waves = 4 q-heads x 2 halves.
// K/V double-buffered, ONE barrier per kv-tile; Q frags in regs (pre-scaled);
// softmax in exp2 domain with deferred row-sum reduction.

__global__ __launch_bounds__(512)
void attn_kernel(const unsigned short* __restrict__ Qb, const unsigned short* __restrict__ Kb,
                 const unsigned short* __restrict__ Vtb, unsigned short* __restrict__ Ob)
{
  __shared__ __align__(16) unsigned short Kl[2][64*32];   // [kv][d]
  __shared__ __align__(16) unsigned short Vl[2][32*64];   // [d][kv]
  __shared__ __align__(16) unsigned short Pl[8][32*64];   // per-wave [q][kv]
  const int tid = threadIdx.x;
  const int w  = tid >> 6, l = tid & 63;
  const int lg = l >> 4, ll = l & 15;
  const int qt = 15 - (int)blockIdx.x;      // descending: heavy blocks first
  const int hk = blockIdx.y, b = blockIdx.z;
  const int h  = hk*4 + (w & 3);
  const int half = w >> 2;
  const int q0 = qt*64 + half*32;           // wave's q-row base within seq

  // Q A-operand frags (rows q0+mi*16+ll, k = d = lg*8+j), pre-scaled in GEMM
  short8 qf[2];
#pragma unroll
  for (int mi = 0; mi < 2; ++mi)
    qf[mi] = *(const short8*)&Qb[((size_t)b*SEQ + q0 + mi*16 + ll)*DM + h*32 + (lg<<3)];

  float4v o[2][2];
  float mrow[2][4], lrow[2][4];
#pragma unroll
  for (int mi = 0; mi < 2; ++mi)
#pragma unroll
    for (int r = 0; r < 4; ++r) {
      o[mi][0][r] = 0.f; o[mi][1][r] = 0.f;
      mrow[mi][r] = -1e30f; lrow[mi][r] = 0.f;
    }

  // staging: waves 0-3 stage K tile (256 x 16B), waves 4-7 stage V tile
  const bool sK = (w < 4);
  const int st = sK ? tid : tid - 256;
  auto stage = [&](int kvt, int bufi) {
    if (sK) {
      int kv = st >> 2, c = st & 3, cl = c ^ (kv & 3);
      load_lds16(&Kb[((size_t)b*SEQ + kvt*64 + kv)*KVD + hk*32 + cl*8],
                 &Kl[bufi][(w*64)*8]);
    } else {
      int d = st >> 3, c8 = st & 7, cl8 = c8 ^ (d & 7);
      load_lds16(&Vtb[((size_t)b*KVD + hk*32 + d)*SEQ + kvt*64 + cl8*8],
                 &Vl[bufi][((w-4)*64)*8]);
    }
  };

  stage(0, 0);
  __syncthreads();
  int buf = 0;
  for (int kvt = 0; kvt <= qt; ++kvt) {
    if (kvt < qt) stage(kvt+1, buf^1);     // issue next-tile loads EARLY (T3)

    // ---- S = Q K^T : lane holds rows q=mi*16+lg*4+r, col kv=ni*16+ll
    short8 kf[4];
#pragma unroll
    for (int ni = 0; ni < 4; ++ni) {
      int kv = ni*16 + ll;
      kf[ni] = *(const short8*)&Kl[buf][kv*32 + ((lg ^ (kv&3)) << 3)];
    }
    float sc[2][4][4];
    __builtin_amdgcn_s_setprio(1);
#pragma unroll
    for (int mi = 0; mi < 2; ++mi)
#pragma unroll
      for (int ni = 0; ni < 4; ++ni) {
        float4v s = __builtin_amdgcn_mfma_f32_16x16x32_bf16(qf[mi], kf[ni],
                       (float4v){0,0,0,0}, 0,0,0);
#pragma unroll
        for (int r = 0; r < 4; ++r) sc[mi][ni][r] = s[r];
      }
    __builtin_amdgcn_s_setprio(0);

    if (kvt == qt) {                        // causal mask (diagonal tile only)
#pragma unroll
      for (int mi = 0; mi < 2; ++mi)
#pragma unroll
        for (int ni = 0; ni < 4; ++ni)
#pragma unroll
          for (int r = 0; r < 4; ++r) {
            int qloc = half*32 + mi*16 + lg*4 + r;
            int kvloc = ni*16 + ll;
            if (kvloc > qloc) sc[mi][ni][r] = -1e30f;
          }
    }

    // ---- online softmax (exp2 domain; row-sum kept as per-lane partial)
    float mt[2][4];
#pragma unroll
    for (int mi = 0; mi < 2; ++mi)
#pragma unroll
      for (int r = 0; r < 4; ++r)
        mt[mi][r] = fmaxf(fmaxf(sc[mi][0][r], sc[mi][1][r]),
                          fmaxf(sc[mi][2][r], sc[mi][3][r]));
#pragma unroll
    for (int off = 1; off <= 8; off <<= 1)
#pragma unroll
      for (int mi = 0; mi < 2; ++mi)
#pragma unroll
        for (int r = 0; r < 4; ++r)
          mt[mi][r] = fmaxf(mt[mi][r], __shfl_xor(mt[mi][r], off));

#pragma unroll
    for (int mi = 0; mi < 2; ++mi)
#pragma unroll
      for (int r = 0; r < 4; ++r) {
        float mn = fmaxf(mrow[mi][r], mt[mi][r]);
        float corr = fexp2(mrow[mi][r] - mn);
        mrow[mi][r] = mn;
        float s0 = 0.f;
#pragma unroll
        for (int ni = 0; ni < 4; ++ni) {
          float p = fexp2(sc[mi][ni][r] - mn);
          sc[mi][ni][r] = p;
          s0 += p;
        }
        lrow[mi][r] = lrow[mi][r]*corr + s0;     // partial over this lane's cols
        o[mi][0][r] *= corr; o[mi][1][r] *= corr;
      }

    // ---- P -> per-wave LDS (XOR-swizzled) for PV A-operand relayout
    unsigned short* Pw = &Pl[w][0];
#pragma unroll
    for (int mi = 0; mi < 2; ++mi)
#pragma unroll
      for (int ni = 0; ni < 4; ++ni)
#pragma unroll
        for (int r = 0; r < 4; ++r) {
          int row = mi*16 + lg*4 + r;
          int col = ni*16 + ll;
          Pw[row*64 + (col ^ ((row & 7) << 3))] = f2bf(sc[mi][ni][r]);
        }

    // ---- O += P V
    __builtin_amdgcn_s_setprio(1);
#pragma unroll
    for (int mi = 0; mi < 2; ++mi)
#pragma unroll
      for (int kk = 0; kk < 2; ++kk) {
        int kvb = kk*32 + (lg << 3);
        short8 pf = *(const short8*)&Pw[(mi*16+ll)*64 + (kvb ^ ((ll & 7) << 3))];
#pragma unroll
        for (int df = 0; df < 2; ++df) {
          int d = df*16 + ll;
          short8 vf = *(const short8*)&Vl[buf][d*64 + (kvb ^ ((d & 7) << 3))];
          o[mi][df] = __builtin_amdgcn_mfma_f32_16x16x32_bf16(pf, vf, o[mi][df], 0,0,0);
        }
      }
    __builtin_amdgcn_s_setprio(0);

    __syncthreads();                        // single barrier per iter (drains vmcnt)
    buf ^= 1;
  }

  // deferred row-sum reduction + output
#pragma unroll
  for (int mi = 0; mi < 2; ++mi)
#pragma unroll
    for (int r = 0; r < 4; ++r) {
      float s = lrow[mi][r];
#pragma unroll
      for (int off = 1; off <= 8; off <<= 1) s += __shfl_xor(s, off);
      float inv = 1.f / s;
      size_t tok = (size_t)b*SEQ + q0 + mi*16 + lg*4 + r;
      Ob[tok*DM + h*32 + ll]      = f2bf(o[mi][0][r] * inv);
      Ob[tok*DM + h*32 + 16 + ll] = f2bf(o[mi][1][r] * inv);
    }
}

// ---- launch -----------------------------------------------------------------

extern "C" void kernel_launch(void* const* d_in, const int* in_sizes, int n_in,
                              void* d_out, int out_size, void* d_ws, size_t ws_size,
                              hipStream_t stream)
{
  const float* x  = (const float*)d_in[0];
  const float* Wq = (const float*)d_in[1];
  const float* Wk = (const float*)d_in[2];
  const float* Wv = (const float*)d_in[3];
  const float* Wo = (const float*)d_in[4];
  const float* bo = (const float*)d_in[5];
  float* out = (float*)d_out;

  char* ws = (char*)d_ws;
  const size_t MB = 1u << 20;
  unsigned short* xb    = (unsigned short*)(ws + 0*MB);   // 8 MB
  unsigned short* Wqkvb = (unsigned short*)(ws + 8*MB);   // 3 MB [1536][1024]
  unsigned short* Wob   = (unsigned short*)(ws + 11*MB);  // 2 MB
  float*          rc    = (float*)(ws + 13*MB);           // 2 MB [1024][512]
  float*          rs    = (float*)(ws + 15*MB);           // 2 MB
  unsigned short* Qb    = (unsigned short*)(ws + 17*MB);  // 8 MB [4096][1024]
  unsigned short* Kb    = (unsigned short*)(ws + 25*MB);  // 2 MB [4096][256]
  unsigned short* Vt    = (unsigned short*)(ws + 27*MB);  // 2 MB [4][256][1024]
  unsigned short* Ob    = (unsigned short*)(ws + 29*MB);  // 8 MB [4096][1024]
  if (ws_size < 37*MB) return;

  {
    const int total = 1703936 + SEQ*512;
    const int blocks = (total + 255) / 256;
    prep_kernel<<<blocks, 256, 0, stream>>>(x, Wq, Wk, Wv, Wo, xb, Wqkvb, Wob, rc, rs);
  }
  gemm_nt<0><<<dim3(32, 12), 256, 0, stream>>>(xb, Wqkvb, Qb, Kb, Vt, nullptr, nullptr, rc, rs);
  attn_kernel<<<dim3(16, 8, 4), 512, 0, stream>>>(Qb, Kb, Vt, Ob);
  gemm_nt<2><<<dim3(32, 8), 256, 0, stream>>>(Ob, Wob, nullptr, nullptr, nullptr, out, bo, rc, rs);
}

// Round 3
// 107.068 us; speedup vs baseline: 1.5948x; 1.3864x over previous
//
#include <hip/hip_runtime.h>
#include <hip/hip_bf16.h>

typedef __attribute__((ext_vector_type(8))) short short8;
typedef __attribute__((ext_vector_type(4))) short short4v;
typedef __attribute__((ext_vector_type(4))) float float4v;

#define DEV __device__ __forceinline__

constexpr int SEQ = 1024;
constexpr int DM  = 1024;    // d_model
constexpr int KVD = 256;     // kv dim
constexpr int MTOK = 4096;   // batch*seq

// 1/sqrt(32) * log2(e) — folded into Q so softmax uses raw v_exp_f32 (2^x)
constexpr float QSCALE = 0.25503487660444f;

// ---- helpers ----------------------------------------------------------------

DEV void load_lds16(const void* g, void* l) {
  __builtin_amdgcn_global_load_lds(
      (const __attribute__((address_space(1))) unsigned int*)g,
      (__attribute__((address_space(3))) unsigned int*)l, 16, 0, 0);
}

DEV unsigned short f2bf(float f) {   // fp32 -> bf16 RNE
  unsigned int u = __float_as_uint(f);
  u += 0x7fffu + ((u >> 16) & 1u);
  return (unsigned short)(u >> 16);
}

DEV float fexp2(float x) {           // raw 2^x
  float y;
  asm("v_exp_f32 %0, %1" : "=v"(y) : "v"(x));
  return y;
}

DEV unsigned int cvtpk(float lo, float hi) {   // pack 2 f32 -> 2 bf16 (lo->[15:0])
  unsigned int r;
  asm("v_cvt_pk_bf16_f32 %0, %1, %2" : "=v"(r) : "v"(lo), "v"(hi));
  return r;
}

#if __has_builtin(__builtin_amdgcn_mfma_f32_16x16x16bf16_1k)
DEV float4v mfma16(short4v a, short4v b, float4v c) {
  return __builtin_amdgcn_mfma_f32_16x16x16bf16_1k(a, b, c, 0, 0, 0);
}
#else
DEV float4v mfma16(short4v a, short4v b, float4v c) {
  asm("v_mfma_f32_16x16x16_bf16 %0, %1, %2, %0" : "+v"(c) : "v"(a), "v"(b));
  return c;
}
#endif

// ---- prep: fp32->bf16 conversions + rope table ------------------------------

__global__ __launch_bounds__(256)
void prep_kernel(const float* __restrict__ x,  const float* __restrict__ Wq,
                 const float* __restrict__ Wk, const float* __restrict__ Wv,
                 const float* __restrict__ Wo,
                 unsigned short* __restrict__ xb, unsigned short* __restrict__ Wqkvb,
                 unsigned short* __restrict__ Wob,
                 float* __restrict__ rc, float* __restrict__ rs)
{
  const int NX  = (MTOK*DM)/4;          // 1048576
  const int NWQ = (DM*DM)/4;            // 262144
  const int NWK = (KVD*DM)/4;           // 65536
  const int NCONV = NX + NWQ + 2*NWK + NWQ; // 1703936
  int id = blockIdx.x*256 + threadIdx.x;
  if (id < NCONV) {
    const float* src; unsigned short* dst; int u;
    if      (id < NX)            { src = x;  dst = xb;                     u = id; }
    else if (id < NX+NWQ)        { src = Wq; dst = Wqkvb;                  u = id-NX; }
    else if (id < NX+NWQ+NWK)    { src = Wk; dst = Wqkvb + DM*DM;          u = id-(NX+NWQ); }
    else if (id < NX+NWQ+2*NWK)  { src = Wv; dst = Wqkvb + DM*DM+KVD*DM;   u = id-(NX+NWQ+NWK); }
    else                         { src = Wo; dst = Wob;                    u = id-(NX+NWQ+2*NWK); }
    float4 v = ((const float4*)src)[u];
    ushort4 o;
    o.x = f2bf(v.x); o.y = f2bf(v.y); o.z = f2bf(v.z); o.w = f2bf(v.w);
    ((ushort4*)dst)[u] = o;
  } else {
    int id2 = id - NCONV;                 // [0, 1024*512)
    if (id2 < SEQ*512) {
      int pos = id2 >> 9, i = id2 & 511;
      float theta = exp2f((float)i * (-13.287712379549449f/512.0f));
      float ang = (float)pos * theta;
      float sv, cv; sincosf(ang, &sv, &cv);
      rc[id2] = cv; rs[id2] = sv;
    }
  }
}

// ---- NT bf16 MFMA GEMM: C[m][n] = sum_k A[m][k]*B[n][k] ---------------------
// MODE 0: fused QKV epilogue (rope+prescale Q -> Qb, rope K -> Kb, V -> Vt)
// MODE 2: out-projection epilogue (fp32 + bias -> outF)

template<int MODE>
__global__ __launch_bounds__(256)
void gemm_nt(const unsigned short* __restrict__ A, const unsigned short* __restrict__ Bw,
             unsigned short* __restrict__ outQ, unsigned short* __restrict__ outK,
             unsigned short* __restrict__ outVt, float* __restrict__ outF,
             const float* __restrict__ bias,
             const float* __restrict__ rc, const float* __restrict__ rs)
{
  __shared__ __align__(16) unsigned short As[128*32];
  __shared__ __align__(16) unsigned short Bs[128*32];
  const int tid = threadIdx.x;
  const int w  = tid >> 6, l = tid & 63;
  const int lg = l >> 4, ll = l & 15;
  const int wr = w >> 1, wc = w & 1;
  const int brow = blockIdx.x * 128, bcol = blockIdx.y * 128;

  float4v acc[4][4];
#pragma unroll
  for (int i = 0; i < 4; ++i)
#pragma unroll
    for (int j = 0; j < 4; ++j) acc[i][j] = (float4v){0.f,0.f,0.f,0.f};

  auto stage = [&](int kt) {
#pragma unroll
    for (int c = 0; c < 2; ++c) {
      int t = c*256 + w*64 + l;            // chunk id 0..511 (16B chunks)
      int row = t >> 2, ch = t & 3;
      int cl = ch ^ (row & 3);             // read-side XOR swizzle pre-applied to src
      load_lds16(A  + (size_t)(brow+row)*DM + kt + cl*8, &As[(c*256 + w*64)*8]);
      load_lds16(Bw + (size_t)(bcol+row)*DM + kt + cl*8, &Bs[(c*256 + w*64)*8]);
    }
  };

  stage(0);
  for (int kt = 0; kt < DM/32; ++kt) {
    __syncthreads();
    short8 af[4], bf[4];
#pragma unroll
    for (int mi = 0; mi < 4; ++mi) {
      int row = wr*64 + mi*16 + ll;
      af[mi] = *(const short8*)&As[row*32 + ((lg ^ (row&3)) << 3)];
    }
#pragma unroll
    for (int ni = 0; ni < 4; ++ni) {
      int col = wc*64 + ni*16 + ll;
      bf[ni] = *(const short8*)&Bs[col*32 + ((lg ^ (col&3)) << 3)];
    }
#pragma unroll
    for (int mi = 0; mi < 4; ++mi)
#pragma unroll
      for (int ni = 0; ni < 4; ++ni)
        acc[mi][ni] = __builtin_amdgcn_mfma_f32_16x16x32_bf16(af[mi], bf[ni], acc[mi][ni], 0,0,0);
    __syncthreads();
    if (kt + 1 < DM/32) stage((kt+1)*32);
  }

  // epilogue: C/D layout col=lane&15, row=(lane>>4)*4+r
#pragma unroll
  for (int mi = 0; mi < 4; ++mi)
#pragma unroll
    for (int ni = 0; ni < 4; ++ni)
#pragma unroll
      for (int r = 0; r < 4; ++r) {
        int m = brow + wr*64 + mi*16 + lg*4 + r;
        int n = bcol + wc*64 + ni*16 + ll;
        float v = acc[mi][ni][r];
        if constexpr (MODE == 0) {
          float p = __shfl_xor(v, 1);      // rope partner col n^1 = lane l^1
          if (n < DM) {                    // Q
            int pos = m & (SEQ-1);
            int i = n >> 1;
            float ct = rc[pos*512 + i], st = rs[pos*512 + i];
            v = (n & 1) ? (v*ct + p*st) : (v*ct - p*st);
            outQ[(size_t)m*DM + n] = f2bf(v * QSCALE);
          } else if (n < DM + KVD) {       // K
            int nk = n - DM;
            int pos = m & (SEQ-1);
            int i = nk >> 1;
            float ct = rc[pos*512 + i], st = rs[pos*512 + i];
            v = (nk & 1) ? (v*ct + p*st) : (v*ct - p*st);
            outK[(size_t)m*KVD + nk] = f2bf(v);
          } else {                         // V -> transposed Vt[b][nv][s]
            int nv = n - DM - KVD;
            outVt[((size_t)(m >> 10)*KVD + nv)*SEQ + (m & (SEQ-1))] = f2bf(v);
          }
        } else {
          outF[(size_t)m*DM + n] = v + bias[n];
        }
      }
}

// ---- causal GQA flash attention v3: swapped-operand, LDS-free softmax/P -----
// grid (16 qtile-pairs, 8 kv-heads, 4 batch); 256 thr = 4 waves = 4 q-heads.
// Each block handles q-tiles (31-i) then (i): uniformly 17 kv-iterations.
// S^T = mfma(K,Q) -> q is lane-local column; P -> PV via cvt_pk, no LDS.
// O^T = mfma(V^T, P) -> rescale/normalize lane-local.

__global__ __launch_bounds__(256)
void attn_kernel(const unsigned short* __restrict__ Qb, const unsigned short* __restrict__ Kb,
                 const unsigned short* __restrict__ Vtb, unsigned short* __restrict__ Ob)
{
  __shared__ __align__(16) unsigned short Kl[2][64*32];   // [kv][d]
  __shared__ __align__(16) unsigned short Vl[2][32*64];   // [d][kv]
  const int tid = threadIdx.x;
  const int w  = tid >> 6, l = tid & 63;
  const int lg = l >> 4, ll = l & 15;
  const int hk = blockIdx.y, b = blockIdx.z;
  const int h  = hk*4 + w;

  auto stage = [&](int kvt, int bufi) {
    int kv = tid >> 2, c = tid & 3, cl = c ^ (kv & 3);
    load_lds16(&Kb[((size_t)b*SEQ + kvt*64 + kv)*KVD + hk*32 + cl*8],
               &Kl[bufi][(w*64)*8]);
    int d = tid >> 3, c8 = tid & 7, cl8 = c8 ^ (d & 7);
    load_lds16(&Vtb[((size_t)b*KVD + hk*32 + d)*SEQ + kvt*64 + cl8*8],
               &Vl[bufi][(w*64)*8]);
  };

#pragma unroll 1
  for (int ph = 0; ph < 2; ++ph) {
    const int qt = ph ? (int)blockIdx.x : 31 - (int)blockIdx.x;   // pair (31-i, i)
    const int nt = qt/2 + 1;              // kv tiles needed (causal)
    const int q0 = qt*32;

    // Q as B-operand frags: col q = ll, k = d = lg*8+j  (pre-scaled by QSCALE)
    short8 qf[2];
#pragma unroll
    for (int qi = 0; qi < 2; ++qi)
      qf[qi] = *(const short8*)&Qb[((size_t)b*SEQ + q0 + qi*16 + ll)*DM + h*32 + (lg<<3)];

    float4v o[2][2];                      // O^T frag [qi][df]: d=df*16+lg*4+r, q=qi*16+ll
    float mrow[2] = {-1e30f, -1e30f};     // per q (lane-local, q=qi*16+ll)
    float lrow[2] = {0.f, 0.f};           // per-lane partial row sums
#pragma unroll
    for (int qi = 0; qi < 2; ++qi)
#pragma unroll
      for (int df = 0; df < 2; ++df) o[qi][df] = (float4v){0,0,0,0};

    stage(0, 0);
    __syncthreads();
    int buf = 0;
    for (int kvt = 0; kvt < nt; ++kvt) {
      if (kvt + 1 < nt) stage(kvt+1, buf^1);    // issue next-tile loads EARLY

      // ---- S^T = K Q^T : lane holds col q=ll(+16qi), rows kv=ni*16+lg*4+r
      short8 kf[4];
#pragma unroll
      for (int ni = 0; ni < 4; ++ni) {
        int kv = ni*16 + ll;
        kf[ni] = *(const short8*)&Kl[buf][kv*32 + ((lg ^ (kv&3)) << 3)];
      }
      float sc[2][4][4];
      __builtin_amdgcn_s_setprio(1);
#pragma unroll
      for (int qi = 0; qi < 2; ++qi)
#pragma unroll
        for (int ni = 0; ni < 4; ++ni) {
          float4v s = __builtin_amdgcn_mfma_f32_16x16x32_bf16(kf[ni], qf[qi],
                         (float4v){0,0,0,0}, 0,0,0);
#pragma unroll
          for (int r = 0; r < 4; ++r) sc[qi][ni][r] = s[r];
        }
      __builtin_amdgcn_s_setprio(0);

      if (kvt == nt-1) {                  // causal mask (only last tile can violate)
#pragma unroll
        for (int qi = 0; qi < 2; ++qi) {
          int q = q0 + qi*16 + ll;
#pragma unroll
          for (int ni = 0; ni < 4; ++ni)
#pragma unroll
            for (int r = 0; r < 4; ++r) {
              int kv = kvt*64 + ni*16 + lg*4 + r;
              if (kv > q) sc[qi][ni][r] = -1e30f;
            }
        }
      }

      // ---- online softmax: q is lane-local; reduce only across lg (2 shfl)
      short4v pf[2][4];
#pragma unroll
      for (int qi = 0; qi < 2; ++qi) {
        float mt = fmaxf(fmaxf(fmaxf(sc[qi][0][0], sc[qi][0][1]), fmaxf(sc[qi][0][2], sc[qi][0][3])),
                   fmaxf(fmaxf(sc[qi][1][0], sc[qi][1][1]), fmaxf(sc[qi][1][2], sc[qi][1][3])));
        mt = fmaxf(mt,
             fmaxf(fmaxf(fmaxf(sc[qi][2][0], sc[qi][2][1]), fmaxf(sc[qi][2][2], sc[qi][2][3])),
                   fmaxf(fmaxf(sc[qi][3][0], sc[qi][3][1]), fmaxf(sc[qi][3][2], sc[qi][3][3]))));
        mt = fmaxf(mt, __shfl_xor(mt, 16));
        mt = fmaxf(mt, __shfl_xor(mt, 32));
        float mn = fmaxf(mrow[qi], mt);
        float corr = fexp2(mrow[qi] - mn);
        mrow[qi] = mn;
        float s0 = 0.f;
#pragma unroll
        for (int ni = 0; ni < 4; ++ni) {
          float p0 = fexp2(sc[qi][ni][0] - mn);
          float p1 = fexp2(sc[qi][ni][1] - mn);
          float p2 = fexp2(sc[qi][ni][2] - mn);
          float p3 = fexp2(sc[qi][ni][3] - mn);
          s0 += (p0 + p1) + (p2 + p3);
          unsigned int w0 = cvtpk(p0, p1), w1 = cvtpk(p2, p3);
          union { unsigned int u[2]; short4v s4; } cv;
          cv.u[0] = w0; cv.u[1] = w1;
          pf[qi][ni] = cv.s4;
        }
        lrow[qi] = lrow[qi]*corr + s0;
#pragma unroll
        for (int df = 0; df < 2; ++df)
#pragma unroll
          for (int r = 0; r < 4; ++r) o[qi][df][r] *= corr;
      }

      // ---- O^T += V^T P : A = V^T frag (row d=ll(+16df), k=kv), B = P frag
      short4v vf[2][4];
#pragma unroll
      for (int df = 0; df < 2; ++df) {
        int d = df*16 + ll;
#pragma unroll
        for (int ni = 0; ni < 4; ++ni) {
          int ch = ((ni*2 + (lg>>1)) ^ (d & 7));
          vf[df][ni] = *(const short4v*)&Vl[buf][d*64 + (ch<<3) + ((lg&1)<<2)];
        }
      }
      __builtin_amdgcn_s_setprio(1);
#pragma unroll
      for (int qi = 0; qi < 2; ++qi)
#pragma unroll
        for (int df = 0; df < 2; ++df)
#pragma unroll
          for (int ni = 0; ni < 4; ++ni)
            o[qi][df] = mfma16(vf[df][ni], pf[qi][ni], o[qi][df]);
      __builtin_amdgcn_s_setprio(0);

      __syncthreads();                    // single barrier per iter (drains vmcnt)
      buf ^= 1;
    }

    // deferred row-sum reduction (across lg only) + normalized store
#pragma unroll
    for (int qi = 0; qi < 2; ++qi) {
      float s = lrow[qi];
      s += __shfl_xor(s, 16);
      s += __shfl_xor(s, 32);
      float inv = 1.f / s;
      size_t tok = (size_t)b*SEQ + q0 + qi*16 + ll;
#pragma unroll
      for (int df = 0; df < 2; ++df) {
        short4v sv;
#pragma unroll
        for (int r = 0; r < 4; ++r) sv[r] = (short)f2bf(o[qi][df][r] * inv);
        *(short4v*)&Ob[tok*DM + h*32 + df*16 + lg*4] = sv;
      }
    }
  }
}

// ---- launch -----------------------------------------------------------------

extern "C" void kernel_launch(void* const* d_in, const int* in_sizes, int n_in,
                              void* d_out, int out_size, void* d_ws, size_t ws_size,
                              hipStream_t stream)
{
  const float* x  = (const float*)d_in[0];
  const float* Wq = (const float*)d_in[1];
  const float* Wk = (const float*)d_in[2];
  const float* Wv = (const float*)d_in[3];
  const float* Wo = (const float*)d_in[4];
  const float* bo = (const float*)d_in[5];
  float* out = (float*)d_out;

  char* ws = (char*)d_ws;
  const size_t MB = 1u << 20;
  unsigned short* xb    = (unsigned short*)(ws + 0*MB);   // 8 MB
  unsigned short* Wqkvb = (unsigned short*)(ws + 8*MB);   // 3 MB [1536][1024]
  unsigned short* Wob   = (unsigned short*)(ws + 11*MB);  // 2 MB
  float*          rc    = (float*)(ws + 13*MB);           // 2 MB [1024][512]
  float*          rs    = (float*)(ws + 15*MB);           // 2 MB
  unsigned short* Qb    = (unsigned short*)(ws + 17*MB);  // 8 MB [4096][1024]
  unsigned short* Kb    = (unsigned short*)(ws + 25*MB);  // 2 MB [4096][256]
  unsigned short* Vt    = (unsigned short*)(ws + 27*MB);  // 2 MB [4][256][1024]
  unsigned short* Ob    = (unsigned short*)(ws + 29*MB);  // 8 MB [4096][1024]
  if (ws_size < 37*MB) return;

  {
    const int total = 1703936 + SEQ*512;
    const int blocks = (total + 255) / 256;
    prep_kernel<<<blocks, 256, 0, stream>>>(x, Wq, Wk, Wv, Wo, xb, Wqkvb, Wob, rc, rs);
  }
  gemm_nt<0><<<dim3(32, 12), 256, 0, stream>>>(xb, Wqkvb, Qb, Kb, Vt, nullptr, nullptr, rc, rs);
  attn_kernel<<<dim3(16, 8, 4), 256, 0, stream>>>(Qb, Kb, Vt, Ob);
  gemm_nt<2><<<dim3(32, 8), 256, 0, stream>>>(Ob, Wob, nullptr, nullptr, nullptr, out, bo, rc, rs);
}

// Round 4
// 103.200 us; speedup vs baseline: 1.6545x; 1.0375x over previous
//
#include <hip/hip_runtime.h>
#include <hip/hip_bf16.h>

typedef __attribute__((ext_vector_type(8))) short short8;
typedef __attribute__((ext_vector_type(4))) short short4v;
typedef __attribute__((ext_vector_type(4))) float float4v;

#define DEV __device__ __forceinline__

constexpr int SEQ = 1024;
constexpr int DM  = 1024;    // d_model
constexpr int KVD = 256;     // kv dim
constexpr int MTOK = 4096;   // batch*seq

// 1/sqrt(32) * log2(e) — folded into Q so softmax uses raw v_exp_f32 (2^x)
constexpr float QSCALE = 0.25503487660444f;

// ---- helpers ----------------------------------------------------------------

DEV void load_lds16(const void* g, void* l) {
  __builtin_amdgcn_global_load_lds(
      (const __attribute__((address_space(1))) unsigned int*)g,
      (__attribute__((address_space(3))) unsigned int*)l, 16, 0, 0);
}

DEV unsigned short f2bf(float f) {   // fp32 -> bf16 RNE
  unsigned int u = __float_as_uint(f);
  u += 0x7fffu + ((u >> 16) & 1u);
  return (unsigned short)(u >> 16);
}

DEV float fexp2(float x) {           // raw 2^x
  float y;
  asm("v_exp_f32 %0, %1" : "=v"(y) : "v"(x));
  return y;
}

DEV unsigned int cvtpk(float lo, float hi) {   // pack 2 f32 -> 2 bf16 (lo->[15:0])
  unsigned int r;
  asm("v_cvt_pk_bf16_f32 %0, %1, %2" : "=v"(r) : "v"(lo), "v"(hi));
  return r;
}

#if __has_builtin(__builtin_amdgcn_mfma_f32_16x16x16bf16_1k)
DEV float4v mfma16(short4v a, short4v b, float4v c) {
  return __builtin_amdgcn_mfma_f32_16x16x16bf16_1k(a, b, c, 0, 0, 0);
}
#else
DEV float4v mfma16(short4v a, short4v b, float4v c) {
  asm("v_mfma_f32_16x16x16_bf16 %0, %1, %2, %0" : "+v"(c) : "v"(a), "v"(b));
  return c;
}
#endif

#define WAIT_VM(N) asm volatile("s_waitcnt vmcnt(" #N ")" ::: "memory")
#define WAIT_LGKM0 asm volatile("s_waitcnt lgkmcnt(0)" ::: "memory")

// ---- prep: fp32->bf16 conversions + rope table ------------------------------

__global__ __launch_bounds__(256)
void prep_kernel(const float* __restrict__ x,  const float* __restrict__ Wq,
                 const float* __restrict__ Wk, const float* __restrict__ Wv,
                 const float* __restrict__ Wo,
                 unsigned short* __restrict__ xb, unsigned short* __restrict__ Wqkvb,
                 unsigned short* __restrict__ Wob,
                 float* __restrict__ rc, float* __restrict__ rs)
{
  const int NX  = (MTOK*DM)/4;          // 1048576
  const int NWQ = (DM*DM)/4;            // 262144
  const int NWK = (KVD*DM)/4;           // 65536
  const int NCONV = NX + NWQ + 2*NWK + NWQ; // 1703936
  int id = blockIdx.x*256 + threadIdx.x;
  if (id < NCONV) {
    const float* src; unsigned short* dst; int u;
    if      (id < NX)            { src = x;  dst = xb;                     u = id; }
    else if (id < NX+NWQ)        { src = Wq; dst = Wqkvb;                  u = id-NX; }
    else if (id < NX+NWQ+NWK)    { src = Wk; dst = Wqkvb + DM*DM;          u = id-(NX+NWQ); }
    else if (id < NX+NWQ+2*NWK)  { src = Wv; dst = Wqkvb + DM*DM+KVD*DM;   u = id-(NX+NWQ+NWK); }
    else                         { src = Wo; dst = Wob;                    u = id-(NX+NWQ+2*NWK); }
    float4 v = ((const float4*)src)[u];
    ushort4 o;
    o.x = f2bf(v.x); o.y = f2bf(v.y); o.z = f2bf(v.z); o.w = f2bf(v.w);
    ((ushort4*)dst)[u] = o;
  } else {
    int id2 = id - NCONV;                 // [0, 1024*512)
    if (id2 < SEQ*512) {
      int pos = id2 >> 9, i = id2 & 511;
      float theta = exp2f((float)i * (-13.287712379549449f/512.0f));
      float ang = (float)pos * theta;
      float sv, cv; sincosf(ang, &sv, &cv);
      rc[id2] = cv; rs[id2] = sv;
    }
  }
}

// ---- NT bf16 MFMA GEMM: C[m][n] = sum_k A[m][k]*B[n][k] ---------------------
// 128x128 tile, BK=32, 4 waves; 3-deep LDS pipeline, raw s_barrier + counted
// vmcnt (never 0 in main loop). Swizzle g(row)=(row>>1)&3 -> 2-way (free).
// MODE 0: fused QKV epilogue (rope+prescale Q -> Qb, rope K -> Kb, V -> Vt)
// MODE 2: out-projection epilogue (fp32 + bias -> outF)

template<int MODE>
__global__ __launch_bounds__(256)
void gemm_nt(const unsigned short* __restrict__ A, const unsigned short* __restrict__ Bw,
             unsigned short* __restrict__ outQ, unsigned short* __restrict__ outK,
             unsigned short* __restrict__ outVt, float* __restrict__ outF,
             const float* __restrict__ bias,
             const float* __restrict__ rc, const float* __restrict__ rs)
{
  __shared__ __align__(16) unsigned short As[3][128*32];
  __shared__ __align__(16) unsigned short Bs[3][128*32];
  const int tid = threadIdx.x;
  const int w  = tid >> 6, l = tid & 63;
  const int lg = l >> 4, ll = l & 15;
  const int wr = w >> 1, wc = w & 1;
  const int brow = blockIdx.x * 128, bcol = blockIdx.y * 128;

  float4v acc[4][4];
#pragma unroll
  for (int i = 0; i < 4; ++i)
#pragma unroll
    for (int j = 0; j < 4; ++j) acc[i][j] = (float4v){0.f,0.f,0.f,0.f};

  auto stage = [&](int kt, int bi) {
#pragma unroll
    for (int c = 0; c < 2; ++c) {
      int t = c*256 + w*64 + l;            // chunk id 0..511 (16B chunks)
      int row = t >> 2, ch = t & 3;
      int cl = ch ^ ((row >> 1) & 3);      // involution, pre-applied to source
      load_lds16(A  + (size_t)(brow+row)*DM + kt*32 + cl*8, &As[bi][(c*256 + w*64)*8]);
      load_lds16(Bw + (size_t)(bcol+row)*DM + kt*32 + cl*8, &Bs[bi][(c*256 + w*64)*8]);
    }
  };

  stage(0, 0); stage(1, 1); stage(2, 2);   // 12 loads/thread in flight
  int bi = 0;
  for (int kt = 0; kt < 32; ++kt) {
    // retire stage kt (kt+1, kt+2 stay in flight: 8 loads)
    if (kt <= 29)      { WAIT_VM(8); }
    else if (kt == 30) { WAIT_VM(4); }
    else               { WAIT_VM(0); }
    __builtin_amdgcn_s_barrier();

    short8 af[4], bf[4];
#pragma unroll
    for (int mi = 0; mi < 4; ++mi) {
      int row = wr*64 + mi*16 + ll;
      af[mi] = *(const short8*)&As[bi][row*32 + ((lg ^ ((row>>1)&3)) << 3)];
    }
#pragma unroll
    for (int ni = 0; ni < 4; ++ni) {
      int col = wc*64 + ni*16 + ll;
      bf[ni] = *(const short8*)&Bs[bi][col*32 + ((lg ^ ((col>>1)&3)) << 3)];
    }
    WAIT_LGKM0;
    __builtin_amdgcn_sched_barrier(0);
    __builtin_amdgcn_s_barrier();          // all waves done reading buf bi

    if (kt + 3 < 32) stage(kt + 3, bi);    // refill freed buffer

    __builtin_amdgcn_s_setprio(1);
#pragma unroll
    for (int mi = 0; mi < 4; ++mi)
#pragma unroll
      for (int ni = 0; ni < 4; ++ni)
        acc[mi][ni] = __builtin_amdgcn_mfma_f32_16x16x32_bf16(af[mi], bf[ni], acc[mi][ni], 0,0,0);
    __builtin_amdgcn_s_setprio(0);

    bi = (bi == 2) ? 0 : bi + 1;
  }

  // epilogue: C/D layout col=lane&15, row=(lane>>4)*4+r
#pragma unroll
  for (int mi = 0; mi < 4; ++mi)
#pragma unroll
    for (int ni = 0; ni < 4; ++ni)
#pragma unroll
      for (int r = 0; r < 4; ++r) {
        int m = brow + wr*64 + mi*16 + lg*4 + r;
        int n = bcol + wc*64 + ni*16 + ll;
        float v = acc[mi][ni][r];
        if constexpr (MODE == 0) {
          float p = __shfl_xor(v, 1);      // rope partner col n^1 = lane l^1
          if (n < DM) {                    // Q
            int pos = m & (SEQ-1);
            int i = n >> 1;
            float ct = rc[pos*512 + i], st = rs[pos*512 + i];
            v = (n & 1) ? (v*ct + p*st) : (v*ct - p*st);
            outQ[(size_t)m*DM + n] = f2bf(v * QSCALE);
          } else if (n < DM + KVD) {       // K
            int nk = n - DM;
            int pos = m & (SEQ-1);
            int i = nk >> 1;
            float ct = rc[pos*512 + i], st = rs[pos*512 + i];
            v = (nk & 1) ? (v*ct + p*st) : (v*ct - p*st);
            outK[(size_t)m*KVD + nk] = f2bf(v);
          } else {                         // V -> transposed Vt[b][nv][s]
            int nv = n - DM - KVD;
            outVt[((size_t)(m >> 10)*KVD + nv)*SEQ + (m & (SEQ-1))] = f2bf(v);
          }
        } else {
          outF[(size_t)m*DM + n] = v + bias[n];
        }
      }
}

// ---- causal GQA flash attention v4: swapped-operand + 3-deep pipeline -------
// grid (16 qtile-pairs, 8 kv-heads, 4 batch); 256 thr = 4 waves = 4 q-heads.
// Block handles q-tiles (31-i) then (i): uniformly 17 kv-iterations total.
// S^T = mfma(K,Q) -> q lane-local; P via cvt_pk in regs; O^T = mfma(V^T,P).

__global__ __launch_bounds__(256)
void attn_kernel(const unsigned short* __restrict__ Qb, const unsigned short* __restrict__ Kb,
                 const unsigned short* __restrict__ Vtb, unsigned short* __restrict__ Ob)
{
  __shared__ __align__(16) unsigned short Kl[3][64*32];   // [kv][d]
  __shared__ __align__(16) unsigned short Vl[3][32*64];   // [d][kv]
  const int tid = threadIdx.x;
  const int w  = tid >> 6, l = tid & 63;
  const int lg = l >> 4, ll = l & 15;
  const int hk = blockIdx.y, b = blockIdx.z;
  const int h  = hk*4 + w;

  auto stage = [&](int kvt, int bi) {
    int kv = tid >> 2, c = tid & 3, cl = c ^ ((kv >> 1) & 3);
    load_lds16(&Kb[((size_t)b*SEQ + kvt*64 + kv)*KVD + hk*32 + cl*8],
               &Kl[bi][(w*64)*8]);
    int d = tid >> 3, c8 = tid & 7, cl8 = c8 ^ (d & 7);
    load_lds16(&Vtb[((size_t)b*KVD + hk*32 + d)*SEQ + kvt*64 + cl8*8],
               &Vl[bi][(w*64)*8]);
  };

#pragma unroll 1
  for (int ph = 0; ph < 2; ++ph) {
    const int qt = ph ? (int)blockIdx.x : 31 - (int)blockIdx.x;   // pair (31-i, i)
    const int nt = qt/2 + 1;              // kv tiles needed (causal)
    const int q0 = qt*32;

    // Q as B-operand frags: col q = ll, k = d = lg*8+j  (pre-scaled by QSCALE)
    short8 qf[2];
#pragma unroll
    for (int qi = 0; qi < 2; ++qi)
      qf[qi] = *(const short8*)&Qb[((size_t)b*SEQ + q0 + qi*16 + ll)*DM + h*32 + (lg<<3)];

    float4v o[2][2];                      // O^T frag [qi][df]: d=df*16+lg*4+r, q=qi*16+ll
    float mrow[2] = {-1e30f, -1e30f};
    float lrow[2] = {0.f, 0.f};
#pragma unroll
    for (int qi = 0; qi < 2; ++qi)
#pragma unroll
      for (int df = 0; df < 2; ++df) o[qi][df] = (float4v){0,0,0,0};

    WAIT_VM(0);                           // clean ledger (prior stores + qf loads)
    stage(0, 0);
    if (1 < nt) stage(1, 1);
    if (2 < nt) stage(2, 2);

    int bi = 0;
    for (int kvt = 0; kvt < nt; ++kvt) {
      if (kvt + 3 <= nt)      { WAIT_VM(4); }   // stages kvt+1,kvt+2 in flight
      else if (kvt + 2 == nt) { WAIT_VM(2); }
      else                    { WAIT_VM(0); }
      __builtin_amdgcn_s_barrier();

      // ---- all LDS reads for this buffer (K frags + V frags)
      short8 kf[4];
#pragma unroll
      for (int ni = 0; ni < 4; ++ni) {
        int kv = ni*16 + ll;
        kf[ni] = *(const short8*)&Kl[bi][kv*32 + ((lg ^ ((kv>>1)&3)) << 3)];
      }
      short4v vf[2][4];
#pragma unroll
      for (int df = 0; df < 2; ++df) {
        int d = df*16 + ll;
#pragma unroll
        for (int ni = 0; ni < 4; ++ni) {
          int ch = ((ni*2 + (lg>>1)) ^ (d & 7));
          vf[df][ni] = *(const short4v*)&Vl[bi][d*64 + (ch<<3) + ((lg&1)<<2)];
        }
      }
      WAIT_LGKM0;
      __builtin_amdgcn_sched_barrier(0);
      __builtin_amdgcn_s_barrier();       // all waves done reading buf bi

      if (kvt + 3 < nt) stage(kvt + 3, bi);

      // ---- S^T = K Q^T : lane holds col q=ll(+16qi), rows kv=ni*16+lg*4+r
      float sc[2][4][4];
      __builtin_amdgcn_s_setprio(1);
#pragma unroll
      for (int qi = 0; qi < 2; ++qi)
#pragma unroll
        for (int ni = 0; ni < 4; ++ni) {
          float4v s = __builtin_amdgcn_mfma_f32_16x16x32_bf16(kf[ni], qf[qi],
                         (float4v){0,0,0,0}, 0,0,0);
#pragma unroll
          for (int r = 0; r < 4; ++r) sc[qi][ni][r] = s[r];
        }
      __builtin_amdgcn_s_setprio(0);

      if (kvt == nt-1) {                  // causal mask (only last tile)
#pragma unroll
        for (int qi = 0; qi < 2; ++qi) {
          int q = q0 + qi*16 + ll;
#pragma unroll
          for (int ni = 0; ni < 4; ++ni)
#pragma unroll
            for (int r = 0; r < 4; ++r) {
              int kv = kvt*64 + ni*16 + lg*4 + r;
              if (kv > q) sc[qi][ni][r] = -1e30f;
            }
        }
      }

      // ---- online softmax: q lane-local; reduce across lg (2 shfl); exact
      // skip of rescale when row max did not grow (corr == 1).
      short4v pf[2][4];
#pragma unroll
      for (int qi = 0; qi < 2; ++qi) {
        float mt = fmaxf(fmaxf(fmaxf(sc[qi][0][0], sc[qi][0][1]), fmaxf(sc[qi][0][2], sc[qi][0][3])),
                   fmaxf(fmaxf(sc[qi][1][0], sc[qi][1][1]), fmaxf(sc[qi][1][2], sc[qi][1][3])));
        mt = fmaxf(mt,
             fmaxf(fmaxf(fmaxf(sc[qi][2][0], sc[qi][2][1]), fmaxf(sc[qi][2][2], sc[qi][2][3])),
                   fmaxf(fmaxf(sc[qi][3][0], sc[qi][3][1]), fmaxf(sc[qi][3][2], sc[qi][3][3]))));
        mt = fmaxf(mt, __shfl_xor(mt, 16));
        mt = fmaxf(mt, __shfl_xor(mt, 32));

        const bool grow = !__all(mt <= mrow[qi]);
        float mn = grow ? fmaxf(mrow[qi], mt) : mrow[qi];
        float s0 = 0.f;
#pragma unroll
        for (int ni = 0; ni < 4; ++ni) {
          float p0 = fexp2(sc[qi][ni][0] - mn);
          float p1 = fexp2(sc[qi][ni][1] - mn);
          float p2 = fexp2(sc[qi][ni][2] - mn);
          float p3 = fexp2(sc[qi][ni][3] - mn);
          s0 += (p0 + p1) + (p2 + p3);
          unsigned int w0 = cvtpk(p0, p1), w1 = cvtpk(p2, p3);
          union { unsigned int u[2]; short4v s4; } cv;
          cv.u[0] = w0; cv.u[1] = w1;
          pf[qi][ni] = cv.s4;
        }
        if (grow) {
          float corr = fexp2(mrow[qi] - mn);
          mrow[qi] = mn;
          lrow[qi] = lrow[qi]*corr + s0;
#pragma unroll
          for (int df = 0; df < 2; ++df)
#pragma unroll
            for (int r = 0; r < 4; ++r) o[qi][df][r] *= corr;
        } else {
          lrow[qi] += s0;
        }
      }

      // ---- O^T += V^T P
      __builtin_amdgcn_s_setprio(1);
#pragma unroll
      for (int qi = 0; qi < 2; ++qi)
#pragma unroll
        for (int df = 0; df < 2; ++df)
#pragma unroll
          for (int ni = 0; ni < 4; ++ni)
            o[qi][df] = mfma16(vf[df][ni], pf[qi][ni], o[qi][df]);
      __builtin_amdgcn_s_setprio(0);

      bi = (bi == 2) ? 0 : bi + 1;
    }

    // deferred row-sum reduction (across lg only) + normalized store
#pragma unroll
    for (int qi = 0; qi < 2; ++qi) {
      float s = lrow[qi];
      s += __shfl_xor(s, 16);
      s += __shfl_xor(s, 32);
      float inv = 1.f / s;
      size_t tok = (size_t)b*SEQ + q0 + qi*16 + ll;
#pragma unroll
      for (int df = 0; df < 2; ++df) {
        short4v sv;
#pragma unroll
        for (int r = 0; r < 4; ++r) sv[r] = (short)f2bf(o[qi][df][r] * inv);
        *(short4v*)&Ob[tok*DM + h*32 + df*16 + lg*4] = sv;
      }
    }
  }
}

// ---- launch -----------------------------------------------------------------

extern "C" void kernel_launch(void* const* d_in, const int* in_sizes, int n_in,
                              void* d_out, int out_size, void* d_ws, size_t ws_size,
                              hipStream_t stream)
{
  const float* x  = (const float*)d_in[0];
  const float* Wq = (const float*)d_in[1];
  const float* Wk = (const float*)d_in[2];
  const float* Wv = (const float*)d_in[3];
  const float* Wo = (const float*)d_in[4];
  const float* bo = (const float*)d_in[5];
  float* out = (float*)d_out;

  char* ws = (char*)d_ws;
  const size_t MB = 1u << 20;
  unsigned short* xb    = (unsigned short*)(ws + 0*MB);   // 8 MB
  unsigned short* Wqkvb = (unsigned short*)(ws + 8*MB);   // 3 MB [1536][1024]
  unsigned short* Wob   = (unsigned short*)(ws + 11*MB);  // 2 MB
  float*          rc    = (float*)(ws + 13*MB);           // 2 MB [1024][512]
  float*          rs    = (float*)(ws + 15*MB);           // 2 MB
  unsigned short* Qb    = (unsigned short*)(ws + 17*MB);  // 8 MB [4096][1024]
  unsigned short* Kb    = (unsigned short*)(ws + 25*MB);  // 2 MB [4096][256]
  unsigned short* Vt    = (unsigned short*)(ws + 27*MB);  // 2 MB [4][256][1024]
  unsigned short* Ob    = (unsigned short*)(ws + 29*MB);  // 8 MB [4096][1024]
  if (ws_size < 37*MB) return;

  {
    const int total = 1703936 + SEQ*512;
    const int blocks = (total + 255) / 256;
    prep_kernel<<<blocks, 256, 0, stream>>>(x, Wq, Wk, Wv, Wo, xb, Wqkvb, Wob, rc, rs);
  }
  gemm_nt<0><<<dim3(32, 12), 256, 0, stream>>>(xb, Wqkvb, Qb, Kb, Vt, nullptr, nullptr, rc, rs);
  attn_kernel<<<dim3(16, 8, 4), 256, 0, stream>>>(Qb, Kb, Vt, Ob);
  gemm_nt<2><<<dim3(32, 8), 256, 0, stream>>>(Ob, Wob, nullptr, nullptr, nullptr, out, bo, rc, rs);
}

// Round 5
// 99.572 us; speedup vs baseline: 1.7148x; 1.0364x over previous
//
#include <hip/hip_runtime.h>
#include <hip/hip_bf16.h>

typedef __attribute__((ext_vector_type(8))) short short8;
typedef __attribute__((ext_vector_type(4))) short short4v;
typedef __attribute__((ext_vector_type(4))) float float4v;

#define DEV __device__ __forceinline__

constexpr int SEQ = 1024;
constexpr int DM  = 1024;    // d_model
constexpr int KVD = 256;     // kv dim
constexpr int MTOK = 4096;   // batch*seq

// 1/sqrt(32) * log2(e) — folded into Q so softmax uses raw v_exp_f32 (2^x)
constexpr float QSCALE = 0.25503487660444f;

// ---- helpers ----------------------------------------------------------------

DEV void load_lds16(const void* g, void* l) {
  __builtin_amdgcn_global_load_lds(
      (const __attribute__((address_space(1))) unsigned int*)g,
      (__attribute__((address_space(3))) unsigned int*)l, 16, 0, 0);
}

DEV unsigned short f2bf(float f) {   // fp32 -> bf16 RNE
  unsigned int u = __float_as_uint(f);
  u += 0x7fffu + ((u >> 16) & 1u);
  return (unsigned short)(u >> 16);
}

DEV float fexp2(float x) {           // raw 2^x
  float y;
  asm("v_exp_f32 %0, %1" : "=v"(y) : "v"(x));
  return y;
}

DEV unsigned int cvtpk(float lo, float hi) {   // pack 2 f32 -> 2 bf16 (lo->[15:0])
  unsigned int r;
  asm("v_cvt_pk_bf16_f32 %0, %1, %2" : "=v"(r) : "v"(lo), "v"(hi));
  return r;
}

#if __has_builtin(__builtin_amdgcn_mfma_f32_16x16x16bf16_1k)
DEV float4v mfma16(short4v a, short4v b, float4v c) {
  return __builtin_amdgcn_mfma_f32_16x16x16bf16_1k(a, b, c, 0, 0, 0);
}
#else
DEV float4v mfma16(short4v a, short4v b, float4v c) {
  asm("v_mfma_f32_16x16x16_bf16 %0, %1, %2, %0" : "+v"(c) : "v"(a), "v"(b));
  return c;
}
#endif

#define WAIT_VM(N) asm volatile("s_waitcnt vmcnt(" #N ")" ::: "memory")
#define WAIT_LGKM0 asm volatile("s_waitcnt lgkmcnt(0)" ::: "memory")

// ---- prep: fp32->bf16 conversions + rope table ------------------------------

__global__ __launch_bounds__(256)
void prep_kernel(const float* __restrict__ x,  const float* __restrict__ Wq,
                 const float* __restrict__ Wk, const float* __restrict__ Wv,
                 const float* __restrict__ Wo,
                 unsigned short* __restrict__ xb, unsigned short* __restrict__ Wqkvb,
                 unsigned short* __restrict__ Wob,
                 float* __restrict__ rc, float* __restrict__ rs)
{
  const int NX  = (MTOK*DM)/4;          // 1048576
  const int NWQ = (DM*DM)/4;            // 262144
  const int NWK = (KVD*DM)/4;           // 65536
  const int NCONV = NX + NWQ + 2*NWK + NWQ; // 1703936
  int id = blockIdx.x*256 + threadIdx.x;
  if (id < NCONV) {
    const float* src; unsigned short* dst; int u;
    if      (id < NX)            { src = x;  dst = xb;                     u = id; }
    else if (id < NX+NWQ)        { src = Wq; dst = Wqkvb;                  u = id-NX; }
    else if (id < NX+NWQ+NWK)    { src = Wk; dst = Wqkvb + DM*DM;          u = id-(NX+NWQ); }
    else if (id < NX+NWQ+2*NWK)  { src = Wv; dst = Wqkvb + DM*DM+KVD*DM;   u = id-(NX+NWQ+NWK); }
    else                         { src = Wo; dst = Wob;                    u = id-(NX+NWQ+2*NWK); }
    float4 v = ((const float4*)src)[u];
    ushort4 o;
    o.x = f2bf(v.x); o.y = f2bf(v.y); o.z = f2bf(v.z); o.w = f2bf(v.w);
    ((ushort4*)dst)[u] = o;
  } else {
    int id2 = id - NCONV;                 // [0, 1024*512)
    if (id2 < SEQ*512) {
      int pos = id2 >> 9, i = id2 & 511;
      float theta = exp2f((float)i * (-13.287712379549449f/512.0f));
      float ang = (float)pos * theta;
      float sv, cv; sincosf(ang, &sv, &cv);
      rc[id2] = cv; rs[id2] = sv;
    }
  }
}

// ---- NT bf16 MFMA GEMM: C[m][n] = sum_k A[m][k]*B[n][k] ---------------------
// 128x64 tile, BK=32, 4 waves (2x2; wave = 64x32 = 4x2 frags); 3-deep LDS
// pipeline, raw s_barrier + counted vmcnt (never 0 mid-loop). XCD-swizzled
// 1-D grid, M-major flat order (per-XCD chunk reuses ~4 A-panels + B in L2).
// MODE 0: fused QKV epilogue (rope+prescale Q -> Qb, rope K -> Kb, V -> Vt)
// MODE 2: out-projection epilogue (fp32 + bias -> outF)

template<int MODE, int GY>
__global__ __launch_bounds__(256)
void gemm_nt(const unsigned short* __restrict__ A, const unsigned short* __restrict__ Bw,
             unsigned short* __restrict__ outQ, unsigned short* __restrict__ outK,
             unsigned short* __restrict__ outVt, float* __restrict__ outF,
             const float* __restrict__ bias,
             const float* __restrict__ rc, const float* __restrict__ rs)
{
  __shared__ __align__(16) unsigned short As[3][128*32];
  __shared__ __align__(16) unsigned short Bs[3][64*32];
  const int tid = threadIdx.x;
  const int w  = tid >> 6, l = tid & 63;
  const int lg = l >> 4, ll = l & 15;
  const int wr = w >> 1, wc = w & 1;

  // XCD-aware bijective swizzle (nwg = 32*GY, divisible by 8)
  const int bid = (int)blockIdx.x;
  const int f   = (bid & 7) * (4*GY) + (bid >> 3);
  const int brow = (f / GY) * 128, bcol = (f % GY) * 64;

  float4v acc[4][2];
#pragma unroll
  for (int i = 0; i < 4; ++i)
#pragma unroll
    for (int j = 0; j < 2; ++j) acc[i][j] = (float4v){0.f,0.f,0.f,0.f};

  auto stage = [&](int kt, int bi) {
#pragma unroll
    for (int c = 0; c < 2; ++c) {          // A: 512 chunks of 16B
      int t = c*256 + w*64 + l;
      int row = t >> 2, ch = t & 3;
      int cl = ch ^ ((row >> 1) & 3);      // involution, pre-applied to source
      load_lds16(A + (size_t)(brow+row)*DM + kt*32 + cl*8, &As[bi][(c*256 + w*64)*8]);
    }
    {                                      // B: 256 chunks of 16B
      int t = w*64 + l;
      int row = t >> 2, ch = t & 3;
      int cl = ch ^ ((row >> 1) & 3);
      load_lds16(Bw + (size_t)(bcol+row)*DM + kt*32 + cl*8, &Bs[bi][(w*64)*8]);
    }
  };

  stage(0, 0); stage(1, 1); stage(2, 2);   // 9 loads/thread in flight
  int bi = 0;
  for (int kt = 0; kt < 32; ++kt) {
    // retire stage kt (kt+1, kt+2 stay in flight: 6 loads)
    if (kt <= 29)      { WAIT_VM(6); }
    else if (kt == 30) { WAIT_VM(3); }
    else               { WAIT_VM(0); }
    __builtin_amdgcn_s_barrier();

    short8 af[4], bf[2];
#pragma unroll
    for (int mi = 0; mi < 4; ++mi) {
      int row = wr*64 + mi*16 + ll;
      af[mi] = *(const short8*)&As[bi][row*32 + ((lg ^ ((row>>1)&3)) << 3)];
    }
#pragma unroll
    for (int ni = 0; ni < 2; ++ni) {
      int col = wc*32 + ni*16 + ll;
      bf[ni] = *(const short8*)&Bs[bi][col*32 + ((lg ^ ((col>>1)&3)) << 3)];
    }
    WAIT_LGKM0;
    __builtin_amdgcn_sched_barrier(0);
    __builtin_amdgcn_s_barrier();          // all waves done reading buf bi

    if (kt + 3 < 32) stage(kt + 3, bi);    // refill freed buffer

    __builtin_amdgcn_s_setprio(1);
#pragma unroll
    for (int mi = 0; mi < 4; ++mi)
#pragma unroll
      for (int ni = 0; ni < 2; ++ni)
        acc[mi][ni] = __builtin_amdgcn_mfma_f32_16x16x32_bf16(af[mi], bf[ni], acc[mi][ni], 0,0,0);
    __builtin_amdgcn_s_setprio(0);

    bi = (bi == 2) ? 0 : bi + 1;
  }

  // epilogue: C/D layout col=lane&15, row=(lane>>4)*4+r
#pragma unroll
  for (int mi = 0; mi < 4; ++mi)
#pragma unroll
    for (int ni = 0; ni < 2; ++ni)
#pragma unroll
      for (int r = 0; r < 4; ++r) {
        int m = brow + wr*64 + mi*16 + lg*4 + r;
        int n = bcol + wc*32 + ni*16 + ll;
        float v = acc[mi][ni][r];
        if constexpr (MODE == 0) {
          float p = __shfl_xor(v, 1);      // rope partner col n^1 = lane l^1
          if (n < DM) {                    // Q
            int pos = m & (SEQ-1);
            int i = n >> 1;
            float ct = rc[pos*512 + i], st = rs[pos*512 + i];
            v = (n & 1) ? (v*ct + p*st) : (v*ct - p*st);
            outQ[(size_t)m*DM + n] = f2bf(v * QSCALE);
          } else if (n < DM + KVD) {       // K
            int nk = n - DM;
            int pos = m & (SEQ-1);
            int i = nk >> 1;
            float ct = rc[pos*512 + i], st = rs[pos*512 + i];
            v = (nk & 1) ? (v*ct + p*st) : (v*ct - p*st);
            outK[(size_t)m*KVD + nk] = f2bf(v);
          } else {                         // V -> transposed Vt[b][nv][s]
            int nv = n - DM - KVD;
            outVt[((size_t)(m >> 10)*KVD + nv)*SEQ + (m & (SEQ-1))] = f2bf(v);
          }
        } else {
          outF[(size_t)m*DM + n] = v + bias[n];
        }
      }
}

// ---- causal GQA flash attention v4: swapped-operand + 3-deep pipeline -------
// grid (16 qtile-pairs, 8 kv-heads, 4 batch); 256 thr = 4 waves = 4 q-heads.
// Block handles q-tiles (31-i) then (i): uniformly 17 kv-iterations total.
// S^T = mfma(K,Q) -> q lane-local; P via cvt_pk in regs; O^T = mfma(V^T,P).

__global__ __launch_bounds__(256)
void attn_kernel(const unsigned short* __restrict__ Qb, const unsigned short* __restrict__ Kb,
                 const unsigned short* __restrict__ Vtb, unsigned short* __restrict__ Ob)
{
  __shared__ __align__(16) unsigned short Kl[3][64*32];   // [kv][d]
  __shared__ __align__(16) unsigned short Vl[3][32*64];   // [d][kv]
  const int tid = threadIdx.x;
  const int w  = tid >> 6, l = tid & 63;
  const int lg = l >> 4, ll = l & 15;
  const int hk = blockIdx.y, b = blockIdx.z;
  const int h  = hk*4 + w;

  auto stage = [&](int kvt, int bi) {
    int kv = tid >> 2, c = tid & 3, cl = c ^ ((kv >> 1) & 3);
    load_lds16(&Kb[((size_t)b*SEQ + kvt*64 + kv)*KVD + hk*32 + cl*8],
               &Kl[bi][(w*64)*8]);
    int d = tid >> 3, c8 = tid & 7, cl8 = c8 ^ (d & 7);
    load_lds16(&Vtb[((size_t)b*KVD + hk*32 + d)*SEQ + kvt*64 + cl8*8],
               &Vl[bi][(w*64)*8]);
  };

#pragma unroll 1
  for (int ph = 0; ph < 2; ++ph) {
    const int qt = ph ? (int)blockIdx.x : 31 - (int)blockIdx.x;   // pair (31-i, i)
    const int nt = qt/2 + 1;              // kv tiles needed (causal)
    const int q0 = qt*32;

    // Q as B-operand frags: col q = ll, k = d = lg*8+j  (pre-scaled by QSCALE)
    short8 qf[2];
#pragma unroll
    for (int qi = 0; qi < 2; ++qi)
      qf[qi] = *(const short8*)&Qb[((size_t)b*SEQ + q0 + qi*16 + ll)*DM + h*32 + (lg<<3)];

    float4v o[2][2];                      // O^T frag [qi][df]: d=df*16+lg*4+r, q=qi*16+ll
    float mrow[2] = {-1e30f, -1e30f};
    float lrow[2] = {0.f, 0.f};
#pragma unroll
    for (int qi = 0; qi < 2; ++qi)
#pragma unroll
      for (int df = 0; df < 2; ++df) o[qi][df] = (float4v){0,0,0,0};

    WAIT_VM(0);                           // clean ledger (prior stores + qf loads)
    stage(0, 0);
    if (1 < nt) stage(1, 1);
    if (2 < nt) stage(2, 2);

    int bi = 0;
    for (int kvt = 0; kvt < nt; ++kvt) {
      if (kvt + 3 <= nt)      { WAIT_VM(4); }   // stages kvt+1,kvt+2 in flight
      else if (kvt + 2 == nt) { WAIT_VM(2); }
      else                    { WAIT_VM(0); }
      __builtin_amdgcn_s_barrier();

      // ---- all LDS reads for this buffer (K frags + V frags)
      short8 kf[4];
#pragma unroll
      for (int ni = 0; ni < 4; ++ni) {
        int kv = ni*16 + ll;
        kf[ni] = *(const short8*)&Kl[bi][kv*32 + ((lg ^ ((kv>>1)&3)) << 3)];
      }
      short4v vf[2][4];
#pragma unroll
      for (int df = 0; df < 2; ++df) {
        int d = df*16 + ll;
#pragma unroll
        for (int ni = 0; ni < 4; ++ni) {
          int ch = ((ni*2 + (lg>>1)) ^ (d & 7));
          vf[df][ni] = *(const short4v*)&Vl[bi][d*64 + (ch<<3) + ((lg&1)<<2)];
        }
      }
      WAIT_LGKM0;
      __builtin_amdgcn_sched_barrier(0);
      __builtin_amdgcn_s_barrier();       // all waves done reading buf bi

      if (kvt + 3 < nt) stage(kvt + 3, bi);

      // ---- S^T = K Q^T : lane holds col q=ll(+16qi), rows kv=ni*16+lg*4+r
      float sc[2][4][4];
      __builtin_amdgcn_s_setprio(1);
#pragma unroll
      for (int qi = 0; qi < 2; ++qi)
#pragma unroll
        for (int ni = 0; ni < 4; ++ni) {
          float4v s = __builtin_amdgcn_mfma_f32_16x16x32_bf16(kf[ni], qf[qi],
                         (float4v){0,0,0,0}, 0,0,0);
#pragma unroll
          for (int r = 0; r < 4; ++r) sc[qi][ni][r] = s[r];
        }
      __builtin_amdgcn_s_setprio(0);

      if (kvt == nt-1) {                  // causal mask (only last tile)
#pragma unroll
        for (int qi = 0; qi < 2; ++qi) {
          int q = q0 + qi*16 + ll;
#pragma unroll
          for (int ni = 0; ni < 4; ++ni)
#pragma unroll
            for (int r = 0; r < 4; ++r) {
              int kv = kvt*64 + ni*16 + lg*4 + r;
              if (kv > q) sc[qi][ni][r] = -1e30f;
            }
        }
      }

      // ---- online softmax: q lane-local; reduce across lg (2 shfl); exact
      // skip of rescale when row max did not grow (corr == 1).
      short4v pf[2][4];
#pragma unroll
      for (int qi = 0; qi < 2; ++qi) {
        float mt = fmaxf(fmaxf(fmaxf(sc[qi][0][0], sc[qi][0][1]), fmaxf(sc[qi][0][2], sc[qi][0][3])),
                   fmaxf(fmaxf(sc[qi][1][0], sc[qi][1][1]), fmaxf(sc[qi][1][2], sc[qi][1][3])));
        mt = fmaxf(mt,
             fmaxf(fmaxf(fmaxf(sc[qi][2][0], sc[qi][2][1]), fmaxf(sc[qi][2][2], sc[qi][2][3])),
                   fmaxf(fmaxf(sc[qi][3][0], sc[qi][3][1]), fmaxf(sc[qi][3][2], sc[qi][3][3]))));
        mt = fmaxf(mt, __shfl_xor(mt, 16));
        mt = fmaxf(mt, __shfl_xor(mt, 32));

        const bool grow = !__all(mt <= mrow[qi]);
        float mn = grow ? fmaxf(mrow[qi], mt) : mrow[qi];
        float s0 = 0.f;
#pragma unroll
        for (int ni = 0; ni < 4; ++ni) {
          float p0 = fexp2(sc[qi][ni][0] - mn);
          float p1 = fexp2(sc[qi][ni][1] - mn);
          float p2 = fexp2(sc[qi][ni][2] - mn);
          float p3 = fexp2(sc[qi][ni][3] - mn);
          s0 += (p0 + p1) + (p2 + p3);
          unsigned int w0 = cvtpk(p0, p1), w1 = cvtpk(p2, p3);
          union { unsigned int u[2]; short4v s4; } cv;
          cv.u[0] = w0; cv.u[1] = w1;
          pf[qi][ni] = cv.s4;
        }
        if (grow) {
          float corr = fexp2(mrow[qi] - mn);
          mrow[qi] = mn;
          lrow[qi] = lrow[qi]*corr + s0;
#pragma unroll
          for (int df = 0; df < 2; ++df)
#pragma unroll
            for (int r = 0; r < 4; ++r) o[qi][df][r] *= corr;
        } else {
          lrow[qi] += s0;
        }
      }

      // ---- O^T += V^T P
      __builtin_amdgcn_s_setprio(1);
#pragma unroll
      for (int qi = 0; qi < 2; ++qi)
#pragma unroll
        for (int df = 0; df < 2; ++df)
#pragma unroll
          for (int ni = 0; ni < 4; ++ni)
            o[qi][df] = mfma16(vf[df][ni], pf[qi][ni], o[qi][df]);
      __builtin_amdgcn_s_setprio(0);

      bi = (bi == 2) ? 0 : bi + 1;
    }

    // deferred row-sum reduction (across lg only) + normalized store
#pragma unroll
    for (int qi = 0; qi < 2; ++qi) {
      float s = lrow[qi];
      s += __shfl_xor(s, 16);
      s += __shfl_xor(s, 32);
      float inv = 1.f / s;
      size_t tok = (size_t)b*SEQ + q0 + qi*16 + ll;
#pragma unroll
      for (int df = 0; df < 2; ++df) {
        short4v sv;
#pragma unroll
        for (int r = 0; r < 4; ++r) sv[r] = (short)f2bf(o[qi][df][r] * inv);
        *(short4v*)&Ob[tok*DM + h*32 + df*16 + lg*4] = sv;
      }
    }
  }
}

// ---- launch -----------------------------------------------------------------

extern "C" void kernel_launch(void* const* d_in, const int* in_sizes, int n_in,
                              void* d_out, int out_size, void* d_ws, size_t ws_size,
                              hipStream_t stream)
{
  const float* x  = (const float*)d_in[0];
  const float* Wq = (const float*)d_in[1];
  const float* Wk = (const float*)d_in[2];
  const float* Wv = (const float*)d_in[3];
  const float* Wo = (const float*)d_in[4];
  const float* bo = (const float*)d_in[5];
  float* out = (float*)d_out;

  char* ws = (char*)d_ws;
  const size_t MB = 1u << 20;
  unsigned short* xb    = (unsigned short*)(ws + 0*MB);   // 8 MB
  unsigned short* Wqkvb = (unsigned short*)(ws + 8*MB);   // 3 MB [1536][1024]
  unsigned short* Wob   = (unsigned short*)(ws + 11*MB);  // 2 MB
  float*          rc    = (float*)(ws + 13*MB);           // 2 MB [1024][512]
  float*          rs    = (float*)(ws + 15*MB);           // 2 MB
  unsigned short* Qb    = (unsigned short*)(ws + 17*MB);  // 8 MB [4096][1024]
  unsigned short* Kb    = (unsigned short*)(ws + 25*MB);  // 2 MB [4096][256]
  unsigned short* Vt    = (unsigned short*)(ws + 27*MB);  // 2 MB [4][256][1024]
  unsigned short* Ob    = (unsigned short*)(ws + 29*MB);  // 8 MB [4096][1024]
  if (ws_size < 37*MB) return;

  {
    const int total = 1703936 + SEQ*512;
    const int blocks = (total + 255) / 256;
    prep_kernel<<<blocks, 256, 0, stream>>>(x, Wq, Wk, Wv, Wo, xb, Wqkvb, Wob, rc, rs);
  }
  // QKV: N=1536 -> GY=24, 768 blocks (3/CU)
  gemm_nt<0, 24><<<dim3(768), 256, 0, stream>>>(xb, Wqkvb, Qb, Kb, Vt, nullptr, nullptr, rc, rs);
  attn_kernel<<<dim3(16, 8, 4), 256, 0, stream>>>(Qb, Kb, Vt, Ob);
  // out-proj: N=1024 -> GY=16, 512 blocks (2/CU)
  gemm_nt<2, 16><<<dim3(512), 256, 0, stream>>>(Ob, Wob, nullptr, nullptr, nullptr, out, bo, rc, rs);
}